// Round 8
// baseline (98.136 us; speedup 1.0000x reference)
//
#include <hip/hip_runtime.h>

// Tree-structured parent-child attention. B=8, N=2048, H=16, D=64, fp32.
// 16 heads x 16 lanes; each lane owns a float4 (16B) of the D=64 row.
//
// R8: 4 nodes per thread (dose-response on memory-level parallelism).
// R7 (2 nodes/thread) gave the first real win, 103.6 -> 94.2 us, even
// though the compiler re-phased the burst (VGPR=24): each phase still
// carries 2x the outstanding loads. Now 4 nodes/thread: 28 logical loads,
// phases widen again. If dur doesn't improve >=3%, the ~5.7 TB/s combined
// L3+HBM delivery is the pattern roofline and we stop.

#define D_DIM   64
#define H_DIM   16
#define N_NODES 2048
#define NPT     4              // nodes per thread

typedef float f32x4 __attribute__((ext_vector_type(4)));

__device__ __forceinline__ float dot4(const float4& a, const float4& b) {
    return a.x * b.x + a.y * b.y + a.z * b.z + a.w * b.w;
}

__global__ __launch_bounds__(256) void tree_attn_kernel(
    const float* __restrict__ Qp,
    const float* __restrict__ Kp,
    const float* __restrict__ Vp,
    const float* __restrict__ Kc,
    const float* __restrict__ Vc,
    float* __restrict__ out)
{
    const int h    = threadIdx.x >> 4;   // 0..15
    const int lane = threadIdx.x & 15;   // 0..15
    const int off  = lane * 4;

    // NPT consecutive nodes per block; never crosses a batch (N % NPT == 0).
    const int bn0 = blockIdx.x * NPT;
    const int b   = bn0 >> 11;                 // / N_NODES
    const int n0  = bn0 & (N_NODES - 1);
    const size_t HD = (size_t)H_DIM * D_DIM;

    const size_t rowP0 = ((size_t)bn0 * H_DIM + h) * D_DIM + off;
    const size_t rowC0 = (((size_t)b * 2 * N_NODES + 2 * n0) * H_DIM + h) * D_DIM + off;

    float4 q[NPT], kp[NPT], kc0[NPT], kc1[NPT], vp[NPT], vc0[NPT], vc1[NPT];

    // ---- 28-load logical burst ----
    #pragma unroll
    for (int i = 0; i < NPT; ++i) {
        const size_t rp = rowP0 + (size_t)i * HD;
        const size_t rc = rowC0 + (size_t)(2 * i) * HD;
        q[i]   = *(const float4*)(Qp + rp);
        kp[i]  = *(const float4*)(Kp + rp);
        kc0[i] = *(const float4*)(Kc + rc);
        kc1[i] = *(const float4*)(Kc + rc + HD);
        vp[i]  = *(const float4*)(Vp + rp);
        vc0[i] = *(const float4*)(Vc + rc);
        vc1[i] = *(const float4*)(Vc + rc + HD);
    }

    asm volatile("" ::: "memory");   // no load may sink below this point

    float s0[NPT], s1[NPT], s2[NPT];
    #pragma unroll
    for (int i = 0; i < NPT; ++i) {
        s0[i] = dot4(q[i], kp[i]);
        s1[i] = dot4(q[i], kc0[i]);
        s2[i] = dot4(q[i], kc1[i]);
    }

    // 16-lane group reduction, NPT nodes interleaved (NPT-way ILP).
    #pragma unroll
    for (int m = 8; m >= 1; m >>= 1) {
        #pragma unroll
        for (int i = 0; i < NPT; ++i) {
            s0[i] += __shfl_xor(s0[i], m);
            s1[i] += __shfl_xor(s1[i], m);
            s2[i] += __shfl_xor(s2[i], m);
        }
    }

    const float scale = 0.125f;  // 1/sqrt(64)
    #pragma unroll
    for (int i = 0; i < NPT; ++i) {
        const float a = s0[i] * scale, c = s1[i] * scale, d = s2[i] * scale;
        const float mx = fmaxf(a, fmaxf(c, d));
        const float e0 = __expf(a - mx);
        const float e1 = __expf(c - mx);
        const float e2 = __expf(d - mx);
        const float inv = 1.0f / (e0 + e1 + e2 + 1e-9f);
        const float w0 = e0 * inv, w1 = e1 * inv, w2 = e2 * inv;

        f32x4 o;
        o.x = w0 * vp[i].x + w1 * vc0[i].x + w2 * vc1[i].x;
        o.y = w0 * vp[i].y + w1 * vc0[i].y + w2 * vc1[i].y;
        o.z = w0 * vp[i].z + w1 * vc0[i].z + w2 * vc1[i].z;
        o.w = w0 * vp[i].w + w1 * vc0[i].w + w2 * vc1[i].w;

        __builtin_nontemporal_store(o, (f32x4*)(out + rowP0 + (size_t)i * HD));
    }
}

extern "C" void kernel_launch(void* const* d_in, const int* in_sizes, int n_in,
                              void* d_out, int out_size, void* d_ws, size_t ws_size,
                              hipStream_t stream) {
    (void)n_in; (void)d_ws; (void)ws_size; (void)out_size; (void)in_sizes;

    const float* Qp = (const float*)d_in[0];
    const float* Kp = (const float*)d_in[1];
    const float* Vp = (const float*)d_in[2];
    const float* Kc = (const float*)d_in[3];
    const float* Vc = (const float*)d_in[4];
    float* out = (float*)d_out;

    const int B = 8;
    dim3 grid((B * N_NODES) / NPT);   // 4096 blocks, 4 nodes each
    dim3 block(256);                  // 16 heads x 16 lanes
    tree_attn_kernel<<<grid, block, 0, stream>>>(Qp, Kp, Vp, Kc, Vc, out);
}

// Round 9
// 81.458 us; speedup vs baseline: 1.2048x; 1.2048x over previous
//
#include <hip/hip_runtime.h>

// Tree-structured parent-child attention. B=8, N=2048, H=16, D=64, fp32.
// 16 heads x 16 lanes; each lane owns a float4 (16B) of the D=64 row.
//
// R9 = R7 (NPT=2 best, 94.2us) + ONE change: non-temporal LOADS on the
// parent streams Qp/Kp/Vp (192MB), regular cacheable loads on the child
// streams Kc/Vc (256MB == L3 capacity). Rationale: R8 showed FETCH_SIZE
// is governed by inter-replay L3 retention (NPT=4 degraded it, +24%
// fetch, regression). Steering retention deliberately: children stay
// L3-resident across replays, parents stream HBM without polluting.
// Mechanism check: FETCH_SIZE 229 -> ~192-205MB. If FETCH unchanged, the
// nt hint doesn't steer TCC replacement -> declare roofline.

#define D_DIM   64
#define H_DIM   16
#define N_NODES 2048

typedef float f32x4 __attribute__((ext_vector_type(4)));

__device__ __forceinline__ float dot4(f32x4 a, f32x4 b) {
    return a.x * b.x + a.y * b.y + a.z * b.z + a.w * b.w;
}

__device__ __forceinline__ f32x4 ntload(const float* p) {
    return __builtin_nontemporal_load((const f32x4*)p);
}

__global__ __launch_bounds__(256) void tree_attn_kernel(
    const float* __restrict__ Qp,
    const float* __restrict__ Kp,
    const float* __restrict__ Vp,
    const float* __restrict__ Kc,
    const float* __restrict__ Vc,
    float* __restrict__ out)
{
    const int h    = threadIdx.x >> 4;   // 0..15
    const int lane = threadIdx.x & 15;   // 0..15
    const int off  = lane * 4;

    // Two consecutive nodes per block; pairs never cross a batch (N even).
    const int bn0 = blockIdx.x * 2;
    const int b   = bn0 >> 11;                 // / N_NODES
    const int n0  = bn0 & (N_NODES - 1);

    const size_t HD = (size_t)H_DIM * D_DIM;
    const size_t rowP0  = ((size_t)bn0 * H_DIM + h) * D_DIM + off;
    const size_t rowP1  = rowP0 + HD;
    const size_t rowC00 = (((size_t)b * 2 * N_NODES + 2 * n0) * H_DIM + h) * D_DIM + off;
    const size_t rowC01 = rowC00 + HD;
    const size_t rowC10 = rowC01 + HD;
    const size_t rowC11 = rowC10 + HD;

    // ---- 14-load burst: parents NT (early-evict), children cacheable ----
    f32x4 qa   = ntload(Qp + rowP0);
    f32x4 qb   = ntload(Qp + rowP1);
    f32x4 kpa  = ntload(Kp + rowP0);
    f32x4 kpb  = ntload(Kp + rowP1);
    f32x4 vpa  = ntload(Vp + rowP0);
    f32x4 vpb  = ntload(Vp + rowP1);
    f32x4 kc0a = *(const f32x4*)(Kc + rowC00);
    f32x4 kc1a = *(const f32x4*)(Kc + rowC01);
    f32x4 kc0b = *(const f32x4*)(Kc + rowC10);
    f32x4 kc1b = *(const f32x4*)(Kc + rowC11);
    f32x4 vc0a = *(const f32x4*)(Vc + rowC00);
    f32x4 vc1a = *(const f32x4*)(Vc + rowC01);
    f32x4 vc0b = *(const f32x4*)(Vc + rowC10);
    f32x4 vc1b = *(const f32x4*)(Vc + rowC11);

    asm volatile("" ::: "memory");   // no load may sink below this point

    float s0a = dot4(qa, kpa),  s0b = dot4(qb, kpb);
    float s1a = dot4(qa, kc0a), s1b = dot4(qb, kc0b);
    float s2a = dot4(qa, kc1a), s2b = dot4(qb, kc1b);

    // 16-lane group reduction, two nodes interleaved (2x ILP in the chain).
    #pragma unroll
    for (int m = 8; m >= 1; m >>= 1) {
        s0a += __shfl_xor(s0a, m);  s0b += __shfl_xor(s0b, m);
        s1a += __shfl_xor(s1a, m);  s1b += __shfl_xor(s1b, m);
        s2a += __shfl_xor(s2a, m);  s2b += __shfl_xor(s2b, m);
    }

    const float scale = 0.125f;  // 1/sqrt(64)
    s0a *= scale; s1a *= scale; s2a *= scale;
    s0b *= scale; s1b *= scale; s2b *= scale;

    const float mxa = fmaxf(s0a, fmaxf(s1a, s2a));
    const float mxb = fmaxf(s0b, fmaxf(s1b, s2b));
    const float e0a = __expf(s0a - mxa), e0b = __expf(s0b - mxb);
    const float e1a = __expf(s1a - mxa), e1b = __expf(s1b - mxb);
    const float e2a = __expf(s2a - mxa), e2b = __expf(s2b - mxb);
    const float inva = 1.0f / (e0a + e1a + e2a + 1e-9f);
    const float invb = 1.0f / (e0b + e1b + e2b + 1e-9f);
    const float w0a = e0a * inva, w1a = e1a * inva, w2a = e2a * inva;
    const float w0b = e0b * invb, w1b = e1b * invb, w2b = e2b * invb;

    f32x4 oa, ob;
    oa.x = w0a * vpa.x + w1a * vc0a.x + w2a * vc1a.x;
    ob.x = w0b * vpb.x + w1b * vc0b.x + w2b * vc1b.x;
    oa.y = w0a * vpa.y + w1a * vc0a.y + w2a * vc1a.y;
    ob.y = w0b * vpb.y + w1b * vc0b.y + w2b * vc1b.y;
    oa.z = w0a * vpa.z + w1a * vc0a.z + w2a * vc1a.z;
    ob.z = w0b * vpb.z + w1b * vc0b.z + w2b * vc1b.z;
    oa.w = w0a * vpa.w + w1a * vc0a.w + w2a * vc1a.w;
    ob.w = w0b * vpb.w + w1b * vc0b.w + w2b * vc1b.w;

    __builtin_nontemporal_store(oa, (f32x4*)(out + rowP0));
    __builtin_nontemporal_store(ob, (f32x4*)(out + rowP1));
}

extern "C" void kernel_launch(void* const* d_in, const int* in_sizes, int n_in,
                              void* d_out, int out_size, void* d_ws, size_t ws_size,
                              hipStream_t stream) {
    (void)n_in; (void)d_ws; (void)ws_size; (void)out_size; (void)in_sizes;

    const float* Qp = (const float*)d_in[0];
    const float* Kp = (const float*)d_in[1];
    const float* Vp = (const float*)d_in[2];
    const float* Kc = (const float*)d_in[3];
    const float* Vc = (const float*)d_in[4];
    float* out = (float*)d_out;

    const int B = 8;
    dim3 grid((B * N_NODES) / 2);   // 8192 blocks, 2 nodes each
    dim3 block(256);                // 16 heads x 16 lanes
    tree_attn_kernel<<<grid, block, 0, stream>>>(Qp, Kp, Vp, Kc, Vc, out);
}

// Round 10
// 81.288 us; speedup vs baseline: 1.2073x; 1.0021x over previous
//
#include <hip/hip_runtime.h>

// Tree-structured parent-child attention. B=8, N=2048, H=16, D=64, fp32.
// 16 heads x 16 lanes; each lane owns a float4 (16B) of the D=64 row.
//
// R10 = NPT=4 (R8's MLP dose) + NT parent loads (R9's cache steering).
// R8's NPT=4 regressed via +24% FETCH (parent streams churning L3 across
// replays); R9's nt-bit on Qp/Kp/Vp removes exactly that churn (child set
// = 256MB = L3 capacity stays resident). If the failure mode is gone, the
// per-phase MLP that paid +9% at NPT=2 should pay again on top of 81.5us.
// Pre-commit: dur within +-3% of 81.5 or worse -> revert to R9, ROOFLINE.

#define D_DIM   64
#define H_DIM   16
#define N_NODES 2048
#define NPT     4              // nodes per thread

typedef float f32x4 __attribute__((ext_vector_type(4)));

__device__ __forceinline__ float dot4(f32x4 a, f32x4 b) {
    return a.x * b.x + a.y * b.y + a.z * b.z + a.w * b.w;
}

__device__ __forceinline__ f32x4 ntload(const float* p) {
    return __builtin_nontemporal_load((const f32x4*)p);
}

__global__ __launch_bounds__(256) void tree_attn_kernel(
    const float* __restrict__ Qp,
    const float* __restrict__ Kp,
    const float* __restrict__ Vp,
    const float* __restrict__ Kc,
    const float* __restrict__ Vc,
    float* __restrict__ out)
{
    const int h    = threadIdx.x >> 4;   // 0..15
    const int lane = threadIdx.x & 15;   // 0..15
    const int off  = lane * 4;

    const int bn0 = blockIdx.x * NPT;    // never crosses a batch (N % NPT == 0)
    const int b   = bn0 >> 11;           // / N_NODES
    const int n0  = bn0 & (N_NODES - 1);
    const size_t HD = (size_t)H_DIM * D_DIM;

    const size_t rowP0 = ((size_t)bn0 * H_DIM + h) * D_DIM + off;
    const size_t rowC0 = (((size_t)b * 2 * N_NODES + 2 * n0) * H_DIM + h) * D_DIM + off;

    f32x4 q[NPT], kp[NPT], kc0[NPT], kc1[NPT], vp[NPT], vc0[NPT], vc1[NPT];

    // ---- 28-load logical burst: parents NT, children cacheable ----
    #pragma unroll
    for (int i = 0; i < NPT; ++i) {
        const size_t rp = rowP0 + (size_t)i * HD;
        const size_t rc = rowC0 + (size_t)(2 * i) * HD;
        q[i]   = ntload(Qp + rp);
        kp[i]  = ntload(Kp + rp);
        vp[i]  = ntload(Vp + rp);
        kc0[i] = *(const f32x4*)(Kc + rc);
        kc1[i] = *(const f32x4*)(Kc + rc + HD);
        vc0[i] = *(const f32x4*)(Vc + rc);
        vc1[i] = *(const f32x4*)(Vc + rc + HD);
    }

    asm volatile("" ::: "memory");   // no load may sink below this point

    float s0[NPT], s1[NPT], s2[NPT];
    #pragma unroll
    for (int i = 0; i < NPT; ++i) {
        s0[i] = dot4(q[i], kp[i]);
        s1[i] = dot4(q[i], kc0[i]);
        s2[i] = dot4(q[i], kc1[i]);
    }

    // 16-lane group reduction, NPT nodes interleaved (NPT-way ILP).
    #pragma unroll
    for (int m = 8; m >= 1; m >>= 1) {
        #pragma unroll
        for (int i = 0; i < NPT; ++i) {
            s0[i] += __shfl_xor(s0[i], m);
            s1[i] += __shfl_xor(s1[i], m);
            s2[i] += __shfl_xor(s2[i], m);
        }
    }

    const float scale = 0.125f;  // 1/sqrt(64)
    #pragma unroll
    for (int i = 0; i < NPT; ++i) {
        const float a = s0[i] * scale, c = s1[i] * scale, d = s2[i] * scale;
        const float mx = fmaxf(a, fmaxf(c, d));
        const float e0 = __expf(a - mx);
        const float e1 = __expf(c - mx);
        const float e2 = __expf(d - mx);
        const float inv = 1.0f / (e0 + e1 + e2 + 1e-9f);
        const float w0 = e0 * inv, w1 = e1 * inv, w2 = e2 * inv;

        f32x4 o;
        o.x = w0 * vp[i].x + w1 * vc0[i].x + w2 * vc1[i].x;
        o.y = w0 * vp[i].y + w1 * vc0[i].y + w2 * vc1[i].y;
        o.z = w0 * vp[i].z + w1 * vc0[i].z + w2 * vc1[i].z;
        o.w = w0 * vp[i].w + w1 * vc0[i].w + w2 * vc1[i].w;

        __builtin_nontemporal_store(o, (f32x4*)(out + rowP0 + (size_t)i * HD));
    }
}

extern "C" void kernel_launch(void* const* d_in, const int* in_sizes, int n_in,
                              void* d_out, int out_size, void* d_ws, size_t ws_size,
                              hipStream_t stream) {
    (void)n_in; (void)d_ws; (void)ws_size; (void)out_size; (void)in_sizes;

    const float* Qp = (const float*)d_in[0];
    const float* Kp = (const float*)d_in[1];
    const float* Vp = (const float*)d_in[2];
    const float* Kc = (const float*)d_in[3];
    const float* Vc = (const float*)d_in[4];
    float* out = (float*)d_out;

    const int B = 8;
    dim3 grid((B * N_NODES) / NPT);   // 4096 blocks, 4 nodes each
    dim3 block(256);                  // 16 heads x 16 lanes
    tree_attn_kernel<<<grid, block, 0, stream>>>(Qp, Kp, Vp, Kc, Vc, out);
}